// Round 3
// baseline (167.611 us; speedup 1.0000x reference)
//
#include <hip/hip_runtime.h>
#include <hip/hip_bf16.h>

#define SEQ   2048
#define DM    1024
#define NH    16
#define DH    64
#define MAXD  128

#define LOG2E 1.44269504f

typedef __attribute__((ext_vector_type(8))) short  short8;   // 8 bf16 = 4 VGPRs
typedef __attribute__((ext_vector_type(4))) float  float4v;  // MFMA 16x16 accumulator

__device__ __forceinline__ short8 ld8(const void* p) {
    short8 v; __builtin_memcpy(&v, p, 16); return v;
}
__device__ __forceinline__ void st8(void* p, short8 v) {
    __builtin_memcpy(p, &v, 16);
}
__device__ __forceinline__ short bf16bits(float f) {
    __hip_bfloat16 b = __float2bfloat16(f);
    short s; __builtin_memcpy(&s, &b, 2); return s;
}
// fast bf16 pack: round-half-up (2 VALU ops). Used on P in [0,1].
__device__ __forceinline__ short bf16fast(float f) {
    unsigned u = __builtin_bit_cast(unsigned, f);
    return (short)((u + 0x8000u) >> 16);
}
__device__ __forceinline__ float bits2f(short s) {
    unsigned u = (unsigned)(unsigned short)s << 16;
    return __builtin_bit_cast(float, u);
}
// fp16 pack/unpack for split-KV partials (rel err 2^-11 < bf16's 2^-8)
__device__ __forceinline__ short fp16bits(float f) {
    _Float16 h = (_Float16)f; short s; __builtin_memcpy(&s, &h, 2); return s;
}
__device__ __forceinline__ float f16tof(short s) {
    _Float16 h; __builtin_memcpy(&h, &s, 2); return (float)h;
}
// raw v_exp_f32 (2^x) — bypasses OCML denorm fixup (flush-to-zero is fine here)
__device__ __forceinline__ float fexp2(float x) {
    float r; asm("v_exp_f32 %0, %1" : "=v"(r) : "v"(x)); return r;
}

// async global->LDS, 16 B per lane. lds = WAVE-UNIFORM base (HW adds lane*16).
__device__ __forceinline__ void async16(void* lds, const void* g) {
    __builtin_amdgcn_global_load_lds(
        (const __attribute__((address_space(1))) unsigned int*)g,
        (__attribute__((address_space(3))) unsigned int*)lds, 16, 0, 0);
}

// DPP cross-lane (16-lane group) reductions — VALU-latency, no LDS pipe.
template <int CTRL>
__device__ __forceinline__ float dppmov(float x) {
    return __builtin_bit_cast(float,
        __builtin_amdgcn_update_dpp(0, __builtin_bit_cast(int, x), CTRL, 0xf, 0xf, true));
}
__device__ __forceinline__ float red16max(float x) {
    x = fmaxf(x, dppmov<0xB1>(x));
    x = fmaxf(x, dppmov<0x4E>(x));
    x = fmaxf(x, dppmov<0x141>(x));
    x = fmaxf(x, dppmov<0x140>(x));
    return x;
}
__device__ __forceinline__ float red16sum(float x) {
    x += dppmov<0xB1>(x);
    x += dppmov<0x4E>(x);
    x += dppmov<0x141>(x);
    x += dppmov<0x140>(x);
    return x;
}

// ---------------------------------------------------------------------------
// Fused prep: weight transposes (fp32->bf16) + x fp32->bf16 convert.
// ---------------------------------------------------------------------------
__global__ __launch_bounds__(256) void prep_kernel(
    const float* __restrict__ wq, const float* __restrict__ wo,
    const float* __restrict__ x,
    __hip_bfloat16* __restrict__ wqT, __hip_bfloat16* __restrict__ woT,
    __hip_bfloat16* __restrict__ xb) {
    const int t = threadIdx.x;
    const int bx = blockIdx.x;
    if (bx >= 128) {
        const size_t id = (size_t)(bx - 128) * 32 + blockIdx.y;
        const size_t i  = id * 2048 + t * 8;
        float f[8]; __builtin_memcpy(f, x + i, 32);
        short8 v;
#pragma unroll
        for (int j = 0; j < 8; ++j) v[j] = bf16bits(f[j]);
        st8(xb + i, v);
        return;
    }
    __shared__ __hip_bfloat16 tile[32][33];
    const int tx = t % 32, ty = t / 32;
    const int r0 = blockIdx.y * 32;
    const float* src; __hip_bfloat16* dst; int ss, ds, c0;
    if (bx < 96) { src = wq; dst = wqT; ss = 3 * DM; ds = DM; c0 = bx * 32; }
    else         { src = wo; dst = woT; ss = DM;     ds = DM; c0 = (bx - 96) * 32; }
#pragma unroll
    for (int i = 0; i < 4; ++i)
        tile[ty + i * 8][tx] = __float2bfloat16(src[(size_t)(r0 + ty + i * 8) * ss + c0 + tx]);
    __syncthreads();
#pragma unroll
    for (int i = 0; i < 4; ++i)
        dst[(size_t)(c0 + ty + i * 8) * ds + r0 + tx] = tile[tx][ty + i * 8];
}

// ---------------------------------------------------------------------------
// GEMM1: 128x64 tiles, BK=64 as two BK=32 planes. 768 blocks = 3/CU.
// V-column blocks (col0>=2048) write their tile transposed to vT.
// ---------------------------------------------------------------------------
__global__ __launch_bounds__(256) void gemm_qkv(
    const __hip_bfloat16* __restrict__ A,
    const __hip_bfloat16* __restrict__ BT,
    __hip_bfloat16* __restrict__ C,
    __hip_bfloat16* __restrict__ vTg,
    int M, int N, int K) {
    __shared__ short As[2 * 128 * 32];
    __shared__ short Bs[2 * 64 * 32];
    __shared__ short Tv[64 * 132];

    const int t = threadIdx.x;
    const int w = t >> 6, lane = t & 63;
    const int l15 = lane & 15, quad = lane >> 4;
    const int row0 = blockIdx.y * 128;
    const int col0 = blockIdx.x * 64;
    const int wm = w >> 1, wn = w & 1;

    float4v acc[4][2];
#pragma unroll
    for (int i = 0; i < 4; ++i)
#pragma unroll
        for (int j = 0; j < 2; ++j) acc[i][j] = (float4v){0.f, 0.f, 0.f, 0.f};

    const int mloc0 = lane >> 2;
    const int u     = lane & 3;

    for (int k0 = 0; k0 < K; k0 += 64) {
#pragma unroll
        for (int kc = 0; kc < 2; ++kc) {
#pragma unroll
            for (int i = 0; i < 2; ++i) {
                const int c = 2 * w + i;
                async16(&As[kc * 4096 + c * 512],
                        A + (size_t)(row0 + c * 16 + mloc0) * K + k0 + kc * 32 + u * 8);
            }
            async16(&Bs[kc * 2048 + w * 512],
                    BT + (size_t)(col0 + w * 16 + mloc0) * K + k0 + kc * 32 + u * 8);
        }
        __syncthreads();

#pragma unroll
        for (int kc = 0; kc < 2; ++kc) {
            short8 af[4], bf[2];
#pragma unroll
            for (int mt = 0; mt < 4; ++mt)
                af[mt] = ld8(&As[kc * 4096 + (wm * 64 + mt * 16 + l15) * 32 + quad * 8]);
#pragma unroll
            for (int nt = 0; nt < 2; ++nt)
                bf[nt] = ld8(&Bs[kc * 2048 + (wn * 32 + nt * 16 + l15) * 32 + quad * 8]);
#pragma unroll
            for (int mt = 0; mt < 4; ++mt)
#pragma unroll
                for (int nt = 0; nt < 2; ++nt)
                    acc[mt][nt] = __builtin_amdgcn_mfma_f32_16x16x32_bf16(
                        af[mt], bf[nt], acc[mt][nt], 0, 0, 0);
        }
        __syncthreads();
    }

    if (col0 < 2 * DM) {
#pragma unroll
        for (int mt = 0; mt < 4; ++mt)
#pragma unroll
            for (int nt = 0; nt < 2; ++nt)
#pragma unroll
                for (int r = 0; r < 4; ++r) {
                    const int row = row0 + wm * 64 + mt * 16 + quad * 4 + r;
                    const int col = col0 + wn * 32 + nt * 16 + l15;
                    C[(size_t)row * N + col] = __float2bfloat16(acc[mt][nt][r]);
                }
    } else {
#pragma unroll
        for (int mt = 0; mt < 4; ++mt)
#pragma unroll
            for (int nt = 0; nt < 2; ++nt)
#pragma unroll
                for (int r = 0; r < 4; ++r)
                    Tv[(wn * 32 + nt * 16 + l15) * 132 + wm * 64 + mt * 16 + quad * 4 + r] =
                        bf16bits(acc[mt][nt][r]);
        __syncthreads();
#pragma unroll
        for (int p = 0; p < 4; ++p) {
            const int idx = p * 256 + t;
            const int dl = idx >> 4, uu = idx & 15;
            st8(&vTg[((size_t)(col0 - 2 * DM) + dl) * SEQ + row0 + uu * 8],
                ld8(&Tv[dl * 132 + uu * 8]));
        }
    }
}

// ---------------------------------------------------------------------------
// GEMM3: 64x64 tiles, BK=64. fp32 out. 512 blocks = 2/CU.
// ---------------------------------------------------------------------------
__global__ __launch_bounds__(256) void gemm_out(
    const __hip_bfloat16* __restrict__ A,
    const __hip_bfloat16* __restrict__ BT,
    float* __restrict__ C,
    int M, int N, int K) {
    __shared__ short As[2 * 64 * 32];
    __shared__ short Bs[2 * 64 * 32];

    const int t = threadIdx.x;
    const int w = t >> 6, lane = t & 63;
    const int l15 = lane & 15, quad = lane >> 4;
    const int row0 = blockIdx.y * 64;
    const int col0 = blockIdx.x * 64;
    const int wm = w >> 1, wn = w & 1;

    float4v acc[2][2];
#pragma unroll
    for (int i = 0; i < 2; ++i)
#pragma unroll
        for (int j = 0; j < 2; ++j) acc[i][j] = (float4v){0.f, 0.f, 0.f, 0.f};

    const int mloc0 = lane >> 2;
    const int u     = lane & 3;

    for (int k0 = 0; k0 < K; k0 += 64) {
#pragma unroll
        for (int kc = 0; kc < 2; ++kc) {
            async16(&As[kc * 2048 + w * 512],
                    A + (size_t)(row0 + w * 16 + mloc0) * K + k0 + kc * 32 + u * 8);
            async16(&Bs[kc * 2048 + w * 512],
                    BT + (size_t)(col0 + w * 16 + mloc0) * K + k0 + kc * 32 + u * 8);
        }
        __syncthreads();

#pragma unroll
        for (int kc = 0; kc < 2; ++kc) {
            short8 af[2], bf[2];
#pragma unroll
            for (int mt = 0; mt < 2; ++mt)
                af[mt] = ld8(&As[kc * 2048 + (wm * 32 + mt * 16 + l15) * 32 + quad * 8]);
#pragma unroll
            for (int nt = 0; nt < 2; ++nt)
                bf[nt] = ld8(&Bs[kc * 2048 + (wn * 32 + nt * 16 + l15) * 32 + quad * 8]);
#pragma unroll
            for (int mt = 0; mt < 2; ++mt)
#pragma unroll
                for (int nt = 0; nt < 2; ++nt)
                    acc[mt][nt] = __builtin_amdgcn_mfma_f32_16x16x32_bf16(
                        af[mt], bf[nt], acc[mt][nt], 0, 0, 0);
        }
        __syncthreads();
    }

#pragma unroll
    for (int mt = 0; mt < 2; ++mt)
#pragma unroll
        for (int nt = 0; nt < 2; ++nt)
#pragma unroll
            for (int r = 0; r < 4; ++r) {
                const int row = row0 + wm * 32 + mt * 16 + quad * 4 + r;
                const int col = col0 + wn * 32 + nt * 16 + l15;
                C[(size_t)row * N + col] = acc[mt][nt][r];
            }
}

// ---------------------------------------------------------------------------
// Flash attention, split-KV x2. Body = round-0 structure verbatim (TK=128,
// Pl aliased into Kt, 3 syncthreads/tile, sync staging — the measured-best
// variant; K/V is L2-resident so staging latency is NOT the bottleneck).
// The split doubles the grid to 1024 blocks -> 4 blocks/CU (LDS 34.8 KB x 4
// = 139 KB < 160 KB) -> 16 waves/CU: 2x the latency hiding for the serial
// softmax/MFMA dependency chains that dominate (both pipes <40% busy at 8
// waves/CU). Partials: normalized O in fp16 + per-(row,head) (m,l) fp32.
// grid decode: xcd=id&7; qb=(id>>3)&31; c=(id&7)+8*(id>>8); h=c&15; half=c>>4.
// ---------------------------------------------------------------------------
#define TK    128            // keys per tile
#define NTILE (SEQ / 2 / TK) // 8 tiles per half
#define KS    68             // Kt row stride (shorts), 34 dwords
#define VS    132            // Vt / Pl row stride (shorts), 66 dwords

__global__ __launch_bounds__(256) void attn_part(
    const __hip_bfloat16* __restrict__ qkv,
    const __hip_bfloat16* __restrict__ vT,
    const float* __restrict__ rel_bias,
    short* __restrict__ opart,          // fp16 bits, [half][SEQ][DM]
    float* __restrict__ ml) {           // [half][SEQ][NH][2] = (m, l)
    __shared__ short KtPl[TK * KS];      // Kt [key][d]; later Pl [q][key] stride VS
    __shared__ short Vt[DH * VS];        // [d][key]
    __shared__ float biasL[MAXD];

    const int t = threadIdx.x;
    const int w = t >> 6, lane = t & 63;
    const int l15 = lane & 15, quad = lane >> 4;

    const int id = blockIdx.x;           // XCD swizzle: id%8 = XCD (round-robin)
    const int qb = (id >> 3) & 31;
    const int c  = (id & 7) + 8 * (id >> 8);   // [0,32)
    const int h  = c & 15;
    const int half = c >> 4;
    const int kbase = half * (SEQ / 2);
    const int q0 = qb * 64;
    const int qw = q0 + w * 16;

    if (t < MAXD) biasL[t] = rel_bias[t * NH + h] * LOG2E;

    // persistent Q fragments, pre-scaled by 0.125*log2e (exp2 domain)
    short8 qf[2];
#pragma unroll
    for (int cc = 0; cc < 2; ++cc) {
        short8 raw = ld8(qkv + (size_t)(qw + l15) * (3 * DM) + h * DH + cc * 32 + quad * 8);
#pragma unroll
        for (int j = 0; j < 8; ++j) qf[cc][j] = bf16bits(bits2f(raw[j]) * (0.125f * LOG2E));
    }

    float4v o_acc[4];
#pragma unroll
    for (int nt = 0; nt < 4; ++nt) o_acc[nt] = (float4v){0.f, 0.f, 0.f, 0.f};
    float m_i[4], l_i[4];
#pragma unroll
    for (int r = 0; r < 4; ++r) { m_i[r] = -1e30f; l_i[r] = 0.f; }

    for (int kb = 0; kb < NTILE; ++kb) {
        const int k0 = kbase + kb * TK;
        // stage K [key][d] and V [d][key]
#pragma unroll
        for (int p = 0; p < 4; ++p) {
            const int idx = p * 256 + t;
            const int row = idx >> 3, u = idx & 7;
            st8(&KtPl[row * KS + u * 8],
                ld8(qkv + (size_t)(k0 + row) * (3 * DM) + DM + h * DH + u * 8));
        }
#pragma unroll
        for (int p = 0; p < 4; ++p) {
            const int idx = p * 256 + t;
            const int row = idx >> 4, u = idx & 15;
            st8(&Vt[row * VS + u * 8],
                ld8(vT + (size_t)(h * DH + row) * SEQ + k0 + u * 8));
        }
        __syncthreads();

        // S = Q K^T (exp2 domain)
        float4v s_acc[8];
#pragma unroll
        for (int kt = 0; kt < 8; ++kt) s_acc[kt] = (float4v){0.f, 0.f, 0.f, 0.f};
#pragma unroll
        for (int cc = 0; cc < 2; ++cc)
#pragma unroll
            for (int kt = 0; kt < 8; ++kt) {
                short8 kf = ld8(&KtPl[(kt * 16 + l15) * KS + (cc * 4 + quad) * 8]);
                s_acc[kt] = __builtin_amdgcn_mfma_f32_16x16x32_bf16(qf[cc], kf, s_acc[kt], 0, 0, 0);
            }

        // bias (wave-uniform fast path at max distance)
        float sv[8][4];
        const int dlo = k0 - (qw + 15);
        const int dhi = qw - (k0 + TK - 1);
        if (dlo >= MAXD - 1 || dhi >= MAXD - 1) {
            const float bu = biasL[MAXD - 1];
#pragma unroll
            for (int kt = 0; kt < 8; ++kt)
#pragma unroll
                for (int r = 0; r < 4; ++r) sv[kt][r] = s_acc[kt][r] + bu;
        } else {
#pragma unroll
            for (int kt = 0; kt < 8; ++kt)
#pragma unroll
                for (int r = 0; r < 4; ++r) {
                    const int kg = k0 + kt * 16 + l15;
                    const int qg = qw + quad * 4 + r;
                    int rel = kg - qg; if (rel < 0) rel = -rel;
                    if (rel > MAXD - 1) rel = MAXD - 1;
                    sv[kt][r] = s_acc[kt][r] + biasL[rel];
                }
        }

        // online softmax (exp2 domain, raw v_exp, DPP reductions)
        float rowm[4];
#pragma unroll
        for (int r = 0; r < 4; ++r) {
            float m = sv[0][r];
#pragma unroll
            for (int kt = 1; kt < 8; ++kt) m = fmaxf(m, sv[kt][r]);
            rowm[r] = red16max(m);
        }

        float al[4], rs[4];
#pragma unroll
        for (int r = 0; r < 4; ++r) {
            const float mn = fmaxf(m_i[r], rowm[r]);
            al[r] = fexp2(m_i[r] - mn);
            m_i[r] = mn;
            rs[r] = 0.f;
        }
#pragma unroll
        for (int kt = 0; kt < 8; ++kt)
#pragma unroll
            for (int r = 0; r < 4; ++r) {
                const float p = fexp2(sv[kt][r] - m_i[r]);
                sv[kt][r] = p;
                rs[r] += p;
            }
#pragma unroll
        for (int r = 0; r < 4; ++r) {
            rs[r] = red16sum(rs[r]);
            l_i[r] = l_i[r] * al[r] + rs[r];
        }
#pragma unroll
        for (int nt = 0; nt < 4; ++nt)
#pragma unroll
            for (int r = 0; r < 4; ++r) o_acc[nt][r] *= al[r];

        __syncthreads();   // all waves done reading Kt before Pl overwrites it

        // P -> per-wave LDS (aliased into KtPl, stride VS), fast pack
#pragma unroll
        for (int kt = 0; kt < 8; ++kt)
#pragma unroll
            for (int r = 0; r < 4; ++r)
                KtPl[w * 16 * VS + (quad * 4 + r) * VS + kt * 16 + l15] = bf16fast(sv[kt][r]);

        // O += P V
#pragma unroll
        for (int kc = 0; kc < 4; ++kc) {
            short8 pf = ld8(&KtPl[w * 16 * VS + l15 * VS + kc * 32 + quad * 8]);
#pragma unroll
            for (int nt = 0; nt < 4; ++nt) {
                short8 vf = ld8(&Vt[(nt * 16 + l15) * VS + kc * 32 + quad * 8]);
                o_acc[nt] = __builtin_amdgcn_mfma_f32_16x16x32_bf16(pf, vf, o_acc[nt], 0, 0, 0);
            }
        }
        __syncthreads();
    }

    // epilogue: normalized partial O (fp16) + (m, l) per row
#pragma unroll
    for (int nt = 0; nt < 4; ++nt)
#pragma unroll
        for (int r = 0; r < 4; ++r) {
            const int row = qw + quad * 4 + r;
            const int col = h * DH + nt * 16 + l15;
            opart[((size_t)half * SEQ + row) * DM + col] = fp16bits(o_acc[nt][r] / l_i[r]);
        }
    if (l15 == 0) {
#pragma unroll
        for (int r = 0; r < 4; ++r) {
            const int row = qw + quad * 4 + r;
            float* mp = ml + (((size_t)half * SEQ + row) * NH + h) * 2;
            mp[0] = m_i[r];
            mp[1] = l_i[r];
        }
    }
}

// ---------------------------------------------------------------------------
// Combine the two KV-half partials: out = w1*o1 + w2*o2,
// wi = li * 2^(mi - m) / sum. Memory-bound (~20 MB). 1024 blocks x 256 thr.
// ---------------------------------------------------------------------------
__global__ __launch_bounds__(256) void combine_kernel(
    const short* __restrict__ opart,     // fp16 bits, [half][SEQ][DM]
    const float* __restrict__ ml,        // [half][SEQ][NH][2]
    __hip_bfloat16* __restrict__ attnb) {
    const size_t e = ((size_t)blockIdx.x * 256 + threadIdx.x) * 8;
    const int row = (int)(e >> 10);
    const int c0  = (int)(e & 1023);
    const int h   = c0 >> 6;

    const float* mp1 = ml + ((size_t)row * NH + h) * 2;
    const float* mp2 = mp1 + (size_t)SEQ * NH * 2;
    const float m1 = mp1[0], l1 = mp1[1];
    const float m2 = mp2[0], l2 = mp2[1];
    const float mx = fmaxf(m1, m2);
    const float e1 = fexp2(m1 - mx) * l1;
    const float e2 = fexp2(m2 - mx) * l2;
    const float inv = 1.f / (e1 + e2);
    const float w1 = e1 * inv, w2 = e2 * inv;

    short8 a = ld8(opart + (size_t)row * DM + c0);
    short8 b = ld8(opart + (size_t)SEQ * DM + (size_t)row * DM + c0);
    short8 o;
#pragma unroll
    for (int j = 0; j < 8; ++j)
        o[j] = bf16bits(w1 * f16tof(a[j]) + w2 * f16tof(b[j]));
    st8(attnb + (size_t)row * DM + c0, o);
}

extern "C" void kernel_launch(void* const* d_in, const int* in_sizes, int n_in,
                              void* d_out, int out_size, void* d_ws, size_t ws_size,
                              hipStream_t stream) {
    const float* x        = (const float*)d_in[0];
    const float* w_qkv    = (const float*)d_in[1];
    const float* w_out    = (const float*)d_in[2];
    const float* rel_bias = (const float*)d_in[3];
    float* out = (float*)d_out;

    // ws layout (16-B aligned), 32 MiB total
    char* p = (char*)d_ws;
    __hip_bfloat16* xb    = (__hip_bfloat16*)p;  p += (size_t)SEQ * DM * 2;      // 4 MiB
    __hip_bfloat16* wqT   = (__hip_bfloat16*)p;  p += (size_t)3 * DM * DM * 2;   // 6 MiB
    __hip_bfloat16* woT   = (__hip_bfloat16*)p;  p += (size_t)DM * DM * 2;       // 2 MiB
    __hip_bfloat16* qkvb  = (__hip_bfloat16*)p;  p += (size_t)SEQ * 3 * DM * 2;  // 12 MiB
    __hip_bfloat16* vT    = (__hip_bfloat16*)p;  p += (size_t)DM * SEQ * 2;      // 4 MiB
    __hip_bfloat16* attnb = (__hip_bfloat16*)p;                                  // 4 MiB

    // split-KV partials overlay the xb+wqT region ([0,10MiB)), dead after
    // gemm_qkv: opart fp16 [2][SEQ][DM] = 8 MiB, ml fp32 [2][SEQ][NH][2] = 0.5 MiB
    short* opart = (short*)d_ws;
    float* ml    = (float*)((char*)d_ws + (size_t)2 * SEQ * DM * 2);

    prep_kernel<<<dim3(160, 32), 256, 0, stream>>>(w_qkv, w_out, x, wqT, woT, xb);

    // 1) qkv = x @ w_qkv; V-columns written transposed to vT in-epilogue
    gemm_qkv<<<dim3(3 * DM / 64, SEQ / 128), 256, 0, stream>>>(
        xb, wqT, qkvb, vT, SEQ, 3 * DM, DM);

    // 2) attention: split-KV x2 (1024 blocks -> 16 waves/CU), then combine
    attn_part<<<1024, 256, 0, stream>>>(qkvb, vT, rel_bias, opart, ml);
    combine_kernel<<<1024, 256, 0, stream>>>(opart, ml, attnb);

    // 3) out = attn @ w_out
    gemm_out<<<dim3(DM / 64, SEQ / 64), 256, 0, stream>>>(
        attnb, woT, out, SEQ, DM, DM);
}

// Round 4
// 153.052 us; speedup vs baseline: 1.0951x; 1.0951x over previous
//
#include <hip/hip_runtime.h>
#include <hip/hip_bf16.h>

#define SEQ   2048
#define DM    1024
#define NH    16
#define DH    64
#define MAXD  128

#define LOG2E 1.44269504f

typedef __attribute__((ext_vector_type(8))) short  short8;   // 8 bf16 = 4 VGPRs
typedef __attribute__((ext_vector_type(4))) float  float4v;  // MFMA 16x16 accumulator

__device__ __forceinline__ short8 ld8(const void* p) {
    short8 v; __builtin_memcpy(&v, p, 16); return v;
}
__device__ __forceinline__ void st8(void* p, short8 v) {
    __builtin_memcpy(p, &v, 16);
}
__device__ __forceinline__ short bf16bits(float f) {
    __hip_bfloat16 b = __float2bfloat16(f);
    short s; __builtin_memcpy(&s, &b, 2); return s;
}
__device__ __forceinline__ float bits2f(short s) {
    unsigned u = (unsigned)(unsigned short)s << 16;
    return __builtin_bit_cast(float, u);
}
// pack two floats -> two bf16 (round-half-up; operands in [0,1])
__device__ __forceinline__ unsigned packbf2(float a, float b) {
    unsigned ua = (__builtin_bit_cast(unsigned, a) + 0x8000u) >> 16;
    unsigned ub = (__builtin_bit_cast(unsigned, b) + 0x8000u) & 0xffff0000u;
    return ua | ub;
}
// pack two floats -> two fp16
__device__ __forceinline__ unsigned packh2(float a, float b) {
    _Float16 ha = (_Float16)a, hb = (_Float16)b;
    unsigned short ua, ub;
    __builtin_memcpy(&ua, &ha, 2); __builtin_memcpy(&ub, &hb, 2);
    return (unsigned)ua | ((unsigned)ub << 16);
}
__device__ __forceinline__ float f16tof(short s) {
    _Float16 h; __builtin_memcpy(&h, &s, 2); return (float)h;
}
// raw v_exp_f32 (2^x) — bypasses OCML denorm fixup (flush-to-zero is fine here)
__device__ __forceinline__ float fexp2(float x) {
    float r; asm("v_exp_f32 %0, %1" : "=v"(r) : "v"(x)); return r;
}

// async global->LDS, 16 B per lane. lds = WAVE-UNIFORM base (HW adds lane*16).
__device__ __forceinline__ void async16(void* lds, const void* g) {
    __builtin_amdgcn_global_load_lds(
        (const __attribute__((address_space(1))) unsigned int*)g,
        (__attribute__((address_space(3))) unsigned int*)lds, 16, 0, 0);
}

// ---------------------------------------------------------------------------
// Fused prep: weight transposes (fp32->bf16) + x fp32->bf16 convert.
// ---------------------------------------------------------------------------
__global__ __launch_bounds__(256) void prep_kernel(
    const float* __restrict__ wq, const float* __restrict__ wo,
    const float* __restrict__ x,
    __hip_bfloat16* __restrict__ wqT, __hip_bfloat16* __restrict__ woT,
    __hip_bfloat16* __restrict__ xb) {
    const int t = threadIdx.x;
    const int bx = blockIdx.x;
    if (bx >= 128) {
        const size_t id = (size_t)(bx - 128) * 32 + blockIdx.y;
        const size_t i  = id * 2048 + t * 8;
        float f[8]; __builtin_memcpy(f, x + i, 32);
        short8 v;
#pragma unroll
        for (int j = 0; j < 8; ++j) v[j] = bf16bits(f[j]);
        st8(xb + i, v);
        return;
    }
    __shared__ __hip_bfloat16 tile[32][33];
    const int tx = t % 32, ty = t / 32;
    const int r0 = blockIdx.y * 32;
    const float* src; __hip_bfloat16* dst; int ss, ds, c0;
    if (bx < 96) { src = wq; dst = wqT; ss = 3 * DM; ds = DM; c0 = bx * 32; }
    else         { src = wo; dst = woT; ss = DM;     ds = DM; c0 = (bx - 96) * 32; }
#pragma unroll
    for (int i = 0; i < 4; ++i)
        tile[ty + i * 8][tx] = __float2bfloat16(src[(size_t)(r0 + ty + i * 8) * ss + c0 + tx]);
    __syncthreads();
#pragma unroll
    for (int i = 0; i < 4; ++i)
        dst[(size_t)(c0 + ty + i * 8) * ds + r0 + tx] = tile[tx][ty + i * 8];
}

// ---------------------------------------------------------------------------
// GEMM1: 128x64 tiles, BK=64 as two BK=32 planes. 768 blocks = 3/CU.
// V-column blocks (col0>=2048) write their tile transposed to vT.
// ---------------------------------------------------------------------------
__global__ __launch_bounds__(256) void gemm_qkv(
    const __hip_bfloat16* __restrict__ A,
    const __hip_bfloat16* __restrict__ BT,
    __hip_bfloat16* __restrict__ C,
    __hip_bfloat16* __restrict__ vTg,
    int M, int N, int K) {
    __shared__ short As[2 * 128 * 32];
    __shared__ short Bs[2 * 64 * 32];
    __shared__ short Tv[64 * 132];

    const int t = threadIdx.x;
    const int w = t >> 6, lane = t & 63;
    const int l15 = lane & 15, quad = lane >> 4;
    const int row0 = blockIdx.y * 128;
    const int col0 = blockIdx.x * 64;
    const int wm = w >> 1, wn = w & 1;

    float4v acc[4][2];
#pragma unroll
    for (int i = 0; i < 4; ++i)
#pragma unroll
        for (int j = 0; j < 2; ++j) acc[i][j] = (float4v){0.f, 0.f, 0.f, 0.f};

    const int mloc0 = lane >> 2;
    const int u     = lane & 3;

    for (int k0 = 0; k0 < K; k0 += 64) {
#pragma unroll
        for (int kc = 0; kc < 2; ++kc) {
#pragma unroll
            for (int i = 0; i < 2; ++i) {
                const int c = 2 * w + i;
                async16(&As[kc * 4096 + c * 512],
                        A + (size_t)(row0 + c * 16 + mloc0) * K + k0 + kc * 32 + u * 8);
            }
            async16(&Bs[kc * 2048 + w * 512],
                    BT + (size_t)(col0 + w * 16 + mloc0) * K + k0 + kc * 32 + u * 8);
        }
        __syncthreads();

#pragma unroll
        for (int kc = 0; kc < 2; ++kc) {
            short8 af[4], bf[2];
#pragma unroll
            for (int mt = 0; mt < 4; ++mt)
                af[mt] = ld8(&As[kc * 4096 + (wm * 64 + mt * 16 + l15) * 32 + quad * 8]);
#pragma unroll
            for (int nt = 0; nt < 2; ++nt)
                bf[nt] = ld8(&Bs[kc * 2048 + (wn * 32 + nt * 16 + l15) * 32 + quad * 8]);
#pragma unroll
            for (int mt = 0; mt < 4; ++mt)
#pragma unroll
                for (int nt = 0; nt < 2; ++nt)
                    acc[mt][nt] = __builtin_amdgcn_mfma_f32_16x16x32_bf16(
                        af[mt], bf[nt], acc[mt][nt], 0, 0, 0);
        }
        __syncthreads();
    }

    if (col0 < 2 * DM) {
#pragma unroll
        for (int mt = 0; mt < 4; ++mt)
#pragma unroll
            for (int nt = 0; nt < 2; ++nt)
#pragma unroll
                for (int r = 0; r < 4; ++r) {
                    const int row = row0 + wm * 64 + mt * 16 + quad * 4 + r;
                    const int col = col0 + wn * 32 + nt * 16 + l15;
                    C[(size_t)row * N + col] = __float2bfloat16(acc[mt][nt][r]);
                }
    } else {
#pragma unroll
        for (int mt = 0; mt < 4; ++mt)
#pragma unroll
            for (int nt = 0; nt < 2; ++nt)
#pragma unroll
                for (int r = 0; r < 4; ++r)
                    Tv[(wn * 32 + nt * 16 + l15) * 132 + wm * 64 + mt * 16 + quad * 4 + r] =
                        bf16bits(acc[mt][nt][r]);
        __syncthreads();
#pragma unroll
        for (int p = 0; p < 4; ++p) {
            const int idx = p * 256 + t;
            const int dl = idx >> 4, uu = idx & 15;
            st8(&vTg[((size_t)(col0 - 2 * DM) + dl) * SEQ + row0 + uu * 8],
                ld8(&Tv[dl * 132 + uu * 8]));
        }
    }
}

// ---------------------------------------------------------------------------
// GEMM3: 64x64 tiles, BK=64. fp32 out. 512 blocks = 2/CU.
// ---------------------------------------------------------------------------
__global__ __launch_bounds__(256) void gemm_out(
    const __hip_bfloat16* __restrict__ A,
    const __hip_bfloat16* __restrict__ BT,
    float* __restrict__ C,
    int M, int N, int K) {
    __shared__ short As[2 * 64 * 32];
    __shared__ short Bs[2 * 64 * 32];

    const int t = threadIdx.x;
    const int w = t >> 6, lane = t & 63;
    const int l15 = lane & 15, quad = lane >> 4;
    const int row0 = blockIdx.y * 64;
    const int col0 = blockIdx.x * 64;
    const int wm = w >> 1, wn = w & 1;

    float4v acc[2][2];
#pragma unroll
    for (int i = 0; i < 2; ++i)
#pragma unroll
        for (int j = 0; j < 2; ++j) acc[i][j] = (float4v){0.f, 0.f, 0.f, 0.f};

    const int mloc0 = lane >> 2;
    const int u     = lane & 3;

    for (int k0 = 0; k0 < K; k0 += 64) {
#pragma unroll
        for (int kc = 0; kc < 2; ++kc) {
            async16(&As[kc * 2048 + w * 512],
                    A + (size_t)(row0 + w * 16 + mloc0) * K + k0 + kc * 32 + u * 8);
            async16(&Bs[kc * 2048 + w * 512],
                    BT + (size_t)(col0 + w * 16 + mloc0) * K + k0 + kc * 32 + u * 8);
        }
        __syncthreads();

#pragma unroll
        for (int kc = 0; kc < 2; ++kc) {
            short8 af[2], bf[2];
#pragma unroll
            for (int mt = 0; mt < 2; ++mt)
                af[mt] = ld8(&As[kc * 2048 + (wm * 32 + mt * 16 + l15) * 32 + quad * 8]);
#pragma unroll
            for (int nt = 0; nt < 2; ++nt)
                bf[nt] = ld8(&Bs[kc * 2048 + (wn * 32 + nt * 16 + l15) * 32 + quad * 8]);
#pragma unroll
            for (int mt = 0; mt < 2; ++mt)
#pragma unroll
                for (int nt = 0; nt < 2; ++nt)
                    acc[mt][nt] = __builtin_amdgcn_mfma_f32_16x16x32_bf16(
                        af[mt], bf[nt], acc[mt][nt], 0, 0, 0);
        }
        __syncthreads();
    }

#pragma unroll
    for (int mt = 0; mt < 2; ++mt)
#pragma unroll
        for (int nt = 0; nt < 2; ++nt)
#pragma unroll
            for (int r = 0; r < 4; ++r) {
                const int row = row0 + wm * 32 + mt * 16 + quad * 4 + r;
                const int col = col0 + wn * 32 + nt * 16 + l15;
                C[(size_t)row * N + col] = acc[mt][nt][r];
            }
}

// ---------------------------------------------------------------------------
// Flash attention v4: swapped-operand layout, 32 q-rows/wave — halves LDS
// traffic per q-row (the measured shared-resource bottleneck: round-3 showed
// 2x waves = 0 speedup at 70% computed LDS-pipe busy).
//   S^T = mfma(K, Q): D[key=quad*4+r (+16kt)][q=l15]  -> softmax per-lane
//   O^T = mfma(V, P): D[d=quad*4+r (+16nt)][q=l15]    -> stats stay lane-local
// Each kf/vf ds_read feeds TWO MFMAs (two q-groups). P written as b64 (not
// 32x b16). In-lane 32-value max/sum trees + shfl_xor(16/32) replace DPP
// chains. Skeleton: round-0 sync staging + 3 barriers (proven), round-3
// split-KV x2 + fp16 partial + combine (proven).
// grid = 512: xcd=id&7; qb=(id>>3)&15 (128 rows); c=(id&7)+8*(id>>7);
// h=c&15; half=c>>4.
// ---------------------------------------------------------------------------
#define TK    128            // keys per tile
#define NTILE (SEQ / 2 / TK) // 8 tiles per half
#define KS    68             // Kt row stride (shorts)
#define VS    132            // Vt row stride (shorts)
#define PS    140            // P row stride (shorts): 8B-aligned rows, <=2-way banks

__global__ __launch_bounds__(256, 2) void attn_part(
    const __hip_bfloat16* __restrict__ qkv,
    const __hip_bfloat16* __restrict__ vT,
    const float* __restrict__ rel_bias,
    short* __restrict__ opart,          // fp16 bits, [half][SEQ][DM]
    float* __restrict__ ml) {           // [half][SEQ][NH][2] = (m, l)
    __shared__ short KtP[4 * 32 * PS];   // Kt [128][KS] aliased; later P [w][32][PS]
    __shared__ short Vt[DH * VS];        // [d][key]
    __shared__ float biasL[MAXD];

    const int t = threadIdx.x;
    const int w = t >> 6, lane = t & 63;
    const int l15 = lane & 15, quad = lane >> 4;

    const int id = blockIdx.x;           // XCD swizzle: id%8 = XCD (round-robin)
    const int qb = (id >> 3) & 15;
    const int c  = (id & 7) + 8 * (id >> 7);   // [0,32)
    const int h  = c & 15;
    const int half = c >> 4;
    const int kbase = half * (SEQ / 2);
    const int qw = qb * 128 + w * 32;    // wave's 32 q-rows: qw + qg*16 + l15

    if (t < MAXD) biasL[t] = rel_bias[t * NH + h] * LOG2E;

    // persistent Q fragments (B-operand: col=q=l15, k=d contiguous),
    // pre-scaled by 0.125*log2e (exp2 domain)
    short8 qf[2][2];
#pragma unroll
    for (int qg = 0; qg < 2; ++qg)
#pragma unroll
        for (int cc = 0; cc < 2; ++cc) {
            short8 raw = ld8(qkv + (size_t)(qw + qg * 16 + l15) * (3 * DM) + h * DH + cc * 32 + quad * 8);
#pragma unroll
            for (int j = 0; j < 8; ++j) qf[qg][cc][j] = bf16bits(bits2f(raw[j]) * (0.125f * LOG2E));
        }

    float4v o_acc[4][2];                 // O^T: [nt (d-block)][qg]
#pragma unroll
    for (int nt = 0; nt < 4; ++nt)
#pragma unroll
        for (int qg = 0; qg < 2; ++qg) o_acc[nt][qg] = (float4v){0.f, 0.f, 0.f, 0.f};
    float m_i[2] = {-1e30f, -1e30f}, l_i[2] = {0.f, 0.f};

    short* Pw = &KtP[w * 32 * PS];       // this wave's P region

    for (int kb = 0; kb < NTILE; ++kb) {
        const int k0 = kbase + kb * TK;
        // stage K [key][d] (stride KS) and V [d][key] (stride VS)
#pragma unroll
        for (int p = 0; p < 4; ++p) {
            const int idx = p * 256 + t;
            const int row = idx >> 3, u = idx & 7;
            st8(&KtP[row * KS + u * 8],
                ld8(qkv + (size_t)(k0 + row) * (3 * DM) + DM + h * DH + u * 8));
        }
#pragma unroll
        for (int p = 0; p < 4; ++p) {
            const int idx = p * 256 + t;
            const int row = idx >> 4, u = idx & 15;
            st8(&Vt[row * VS + u * 8],
                ld8(vT + (size_t)(h * DH + row) * SEQ + k0 + u * 8));
        }
        __syncthreads();

        // S^T = mfma(K, Q): each kf read feeds both q-groups
        float4v s_acc[2][8];
#pragma unroll
        for (int qg = 0; qg < 2; ++qg)
#pragma unroll
            for (int kt = 0; kt < 8; ++kt) s_acc[qg][kt] = (float4v){0.f, 0.f, 0.f, 0.f};
#pragma unroll
        for (int cc = 0; cc < 2; ++cc)
#pragma unroll
            for (int kt = 0; kt < 8; ++kt) {
                short8 kf = ld8(&KtP[(kt * 16 + l15) * KS + (cc * 4 + quad) * 8]);
                s_acc[0][kt] = __builtin_amdgcn_mfma_f32_16x16x32_bf16(kf, qf[0][cc], s_acc[0][kt], 0, 0, 0);
                s_acc[1][kt] = __builtin_amdgcn_mfma_f32_16x16x32_bf16(kf, qf[1][cc], s_acc[1][kt], 0, 0, 0);
            }

        // bias in-place (wave-uniform fast path at max distance)
        const int dlo = k0 - (qw + 31);
        const int dhi = qw - (k0 + TK - 1);
        if (dlo >= MAXD - 1 || dhi >= MAXD - 1) {
            const float bu = biasL[MAXD - 1];
#pragma unroll
            for (int qg = 0; qg < 2; ++qg)
#pragma unroll
                for (int kt = 0; kt < 8; ++kt)
#pragma unroll
                    for (int r = 0; r < 4; ++r) s_acc[qg][kt][r] += bu;
        } else {
#pragma unroll
            for (int qg = 0; qg < 2; ++qg) {
                const int qrow = qw + qg * 16 + l15;
#pragma unroll
                for (int kt = 0; kt < 8; ++kt)
#pragma unroll
                    for (int r = 0; r < 4; ++r) {
                        const int kg = k0 + kt * 16 + quad * 4 + r;
                        int rel = kg - qrow; if (rel < 0) rel = -rel;
                        if (rel > MAXD - 1) rel = MAXD - 1;
                        s_acc[qg][kt][r] += biasL[rel];
                    }
            }
        }

        // online softmax: per-lane q (= l15 + 16*qg); in-lane trees + 2 shfl
        float al[2];
#pragma unroll
        for (int qg = 0; qg < 2; ++qg) {
            float mk[8];
#pragma unroll
            for (int kt = 0; kt < 8; ++kt)
                mk[kt] = fmaxf(fmaxf(s_acc[qg][kt][0], s_acc[qg][kt][1]),
                               fmaxf(s_acc[qg][kt][2], s_acc[qg][kt][3]));
            float m = fmaxf(fmaxf(fmaxf(mk[0], mk[1]), fmaxf(mk[2], mk[3])),
                            fmaxf(fmaxf(mk[4], mk[5]), fmaxf(mk[6], mk[7])));
            m = fmaxf(m, __shfl_xor(m, 16, 64));
            m = fmaxf(m, __shfl_xor(m, 32, 64));
            const float mn = fmaxf(m_i[qg], m);
            al[qg] = fexp2(m_i[qg] - mn);
            m_i[qg] = mn;
            float sk[8];
#pragma unroll
            for (int kt = 0; kt < 8; ++kt) {
                float p0 = fexp2(s_acc[qg][kt][0] - mn);
                float p1 = fexp2(s_acc[qg][kt][1] - mn);
                float p2 = fexp2(s_acc[qg][kt][2] - mn);
                float p3 = fexp2(s_acc[qg][kt][3] - mn);
                s_acc[qg][kt][0] = p0; s_acc[qg][kt][1] = p1;
                s_acc[qg][kt][2] = p2; s_acc[qg][kt][3] = p3;
                sk[kt] = (p0 + p1) + (p2 + p3);
            }
            float rs = ((sk[0] + sk[1]) + (sk[2] + sk[3])) +
                       ((sk[4] + sk[5]) + (sk[6] + sk[7]));
            rs += __shfl_xor(rs, 16, 64);
            rs += __shfl_xor(rs, 32, 64);
            l_i[qg] = l_i[qg] * al[qg] + rs;
        }
#pragma unroll
        for (int nt = 0; nt < 4; ++nt)
#pragma unroll
            for (int qg = 0; qg < 2; ++qg)
#pragma unroll
                for (int r = 0; r < 4; ++r) o_acc[nt][qg][r] *= al[qg];

        __syncthreads();   // all waves done reading Kt before P overwrites it

        // P -> own wave's region, b64 stores: P[qlocal][key], 4 keys/store
#pragma unroll
        for (int qg = 0; qg < 2; ++qg)
#pragma unroll
            for (int kt = 0; kt < 8; ++kt) {
                unsigned d0 = packbf2(s_acc[qg][kt][0], s_acc[qg][kt][1]);
                unsigned d1 = packbf2(s_acc[qg][kt][2], s_acc[qg][kt][3]);
                unsigned long long v = (unsigned long long)d0 | ((unsigned long long)d1 << 32);
                __builtin_memcpy(&Pw[(qg * 16 + l15) * PS + kt * 16 + quad * 4], &v, 8);
            }

        // O^T += mfma(V, P): each vf read feeds both q-groups
#pragma unroll
        for (int kc = 0; kc < 4; ++kc) {
            short8 pf0 = ld8(&Pw[l15 * PS + kc * 32 + quad * 8]);
            short8 pf1 = ld8(&Pw[(16 + l15) * PS + kc * 32 + quad * 8]);
#pragma unroll
            for (int nt = 0; nt < 4; ++nt) {
                short8 vf = ld8(&Vt[(nt * 16 + l15) * VS + kc * 32 + quad * 8]);
                o_acc[nt][0] = __builtin_amdgcn_mfma_f32_16x16x32_bf16(vf, pf0, o_acc[nt][0], 0, 0, 0);
                o_acc[nt][1] = __builtin_amdgcn_mfma_f32_16x16x32_bf16(vf, pf1, o_acc[nt][1], 0, 0, 0);
            }
        }
        __syncthreads();
    }

    // epilogue: normalized partial O (fp16, b64 stores) + (m, l) per q-row
#pragma unroll
    for (int qg = 0; qg < 2; ++qg) {
        const float inv = 1.f / l_i[qg];
        const int qrow = qw + qg * 16 + l15;
#pragma unroll
        for (int nt = 0; nt < 4; ++nt) {
            unsigned d0 = packh2(o_acc[nt][qg][0] * inv, o_acc[nt][qg][1] * inv);
            unsigned d1 = packh2(o_acc[nt][qg][2] * inv, o_acc[nt][qg][3] * inv);
            unsigned long long v = (unsigned long long)d0 | ((unsigned long long)d1 << 32);
            __builtin_memcpy(opart + ((size_t)half * SEQ + qrow) * DM + h * DH + nt * 16 + quad * 4, &v, 8);
        }
    }
    if (quad == 0) {
#pragma unroll
        for (int qg = 0; qg < 2; ++qg) {
            const int qrow = qw + qg * 16 + l15;
            float* mp = ml + (((size_t)half * SEQ + qrow) * NH + h) * 2;
            mp[0] = m_i[qg];
            mp[1] = l_i[qg];
        }
    }
}

// ---------------------------------------------------------------------------
// Combine the two KV-half partials: out = w1*o1 + w2*o2,
// wi = li * 2^(mi - m) / sum. Memory-bound (~20 MB). 1024 blocks x 256 thr.
// ---------------------------------------------------------------------------
__global__ __launch_bounds__(256) void combine_kernel(
    const short* __restrict__ opart,     // fp16 bits, [half][SEQ][DM]
    const float* __restrict__ ml,        // [half][SEQ][NH][2]
    __hip_bfloat16* __restrict__ attnb) {
    const size_t e = ((size_t)blockIdx.x * 256 + threadIdx.x) * 8;
    const int row = (int)(e >> 10);
    const int c0  = (int)(e & 1023);
    const int h   = c0 >> 6;

    const float* mp1 = ml + ((size_t)row * NH + h) * 2;
    const float* mp2 = mp1 + (size_t)SEQ * NH * 2;
    const float m1 = mp1[0], l1 = mp1[1];
    const float m2 = mp2[0], l2 = mp2[1];
    const float mx = fmaxf(m1, m2);
    const float e1 = fexp2(m1 - mx) * l1;
    const float e2 = fexp2(m2 - mx) * l2;
    const float inv = 1.f / (e1 + e2);
    const float w1 = e1 * inv, w2 = e2 * inv;

    short8 a = ld8(opart + (size_t)row * DM + c0);
    short8 b = ld8(opart + (size_t)SEQ * DM + (size_t)row * DM + c0);
    short8 o;
#pragma unroll
    for (int j = 0; j < 8; ++j)
        o[j] = bf16bits(w1 * f16tof(a[j]) + w2 * f16tof(b[j]));
    st8(attnb + (size_t)row * DM + c0, o);
}

extern "C" void kernel_launch(void* const* d_in, const int* in_sizes, int n_in,
                              void* d_out, int out_size, void* d_ws, size_t ws_size,
                              hipStream_t stream) {
    const float* x        = (const float*)d_in[0];
    const float* w_qkv    = (const float*)d_in[1];
    const float* w_out    = (const float*)d_in[2];
    const float* rel_bias = (const float*)d_in[3];
    float* out = (float*)d_out;

    // ws layout (16-B aligned), 32 MiB total
    char* p = (char*)d_ws;
    __hip_bfloat16* xb    = (__hip_bfloat16*)p;  p += (size_t)SEQ * DM * 2;      // 4 MiB
    __hip_bfloat16* wqT   = (__hip_bfloat16*)p;  p += (size_t)3 * DM * DM * 2;   // 6 MiB
    __hip_bfloat16* woT   = (__hip_bfloat16*)p;  p += (size_t)DM * DM * 2;       // 2 MiB
    __hip_bfloat16* qkvb  = (__hip_bfloat16*)p;  p += (size_t)SEQ * 3 * DM * 2;  // 12 MiB
    __hip_bfloat16* vT    = (__hip_bfloat16*)p;  p += (size_t)DM * SEQ * 2;      // 4 MiB
    __hip_bfloat16* attnb = (__hip_bfloat16*)p;                                  // 4 MiB

    // split-KV partials overlay the xb+wqT region ([0,10MiB)), dead after
    // gemm_qkv: opart fp16 [2][SEQ][DM] = 8 MiB, ml fp32 [2][SEQ][NH][2] = 0.5 MiB
    short* opart = (short*)d_ws;
    float* ml    = (float*)((char*)d_ws + (size_t)2 * SEQ * DM * 2);

    prep_kernel<<<dim3(160, 32), 256, 0, stream>>>(w_qkv, w_out, x, wqT, woT, xb);

    // 1) qkv = x @ w_qkv; V-columns written transposed to vT in-epilogue
    gemm_qkv<<<dim3(3 * DM / 64, SEQ / 128), 256, 0, stream>>>(
        xb, wqT, qkvb, vT, SEQ, 3 * DM, DM);

    // 2) attention: swapped-layout 32q/wave split-KV x2, then combine
    attn_part<<<512, 256, 0, stream>>>(qkvb, vT, rel_bias, opart, ml);
    combine_kernel<<<1024, 256, 0, stream>>>(opart, ml, attnb);

    // 3) out = attn @ w_out
    gemm_out<<<dim3(DM / 64, SEQ / 64), 256, 0, stream>>>(
        attnb, woT, out, SEQ, DM, DM);
}